// Round 4
// baseline (291.535 us; speedup 1.0000x reference)
//
#include <hip/hip_runtime.h>
#include <stdint.h>

#define BATCH 128
#define LCOUNT 196
#define LP1 197
#define DIM 1024

typedef __bf16 bf16x8 __attribute__((ext_vector_type(8)));
typedef float f32x4 __attribute__((ext_vector_type(4)));

__device__ inline float bf2f(uint16_t h){ union{uint32_t i; float f;} x; x.i = ((uint32_t)h) << 16; return x.f; }
__device__ inline uint32_t f2bf(float f){
  union{float f; uint32_t u;} x; x.f = f;
  uint32_t r = x.u + 0x7fffu + ((x.u >> 16) & 1u);
  return r >> 16;
}
__device__ inline float tanh_fast(float x){
  float e = __expf(2.0f * x);
  return 1.0f - 2.0f / (e + 1.0f);
}

// load 8 contiguous fp32 and convert to bf16x8 (RNE, same as f2bf)
__device__ inline bf16x8 cvt8(const float* p){
  float4 a = *(const float4*)p;
  float4 b = *(const float4*)(p + 4);
  bf16x8 r;
  r[0] = (__bf16)a.x; r[1] = (__bf16)a.y; r[2] = (__bf16)a.z; r[3] = (__bf16)a.w;
  r[4] = (__bf16)b.x; r[5] = (__bf16)b.y; r[6] = (__bf16)b.z; r[7] = (__bf16)b.w;
  return r;
}

// ---------------- GEMM: C[m,n] = act(sum_k A[m,k]*W[n,k] + bias[n]) ----------
// M=128, N=1024, K=1024. A/W may be fp32 (converted in-register) or bf16.
// Split-K: block = one 16x16 output tile; each of 4 waves covers K/4 = 256
// (8 chained MFMAs), partials reduced via LDS. Grid (8,64,z) = 512/GEMM.
struct GemmArgs {
  const void* A;         // [128,1024] fp32 or bf16
  const void* W;         // [1024,1024] fp32 or bf16, row-major [N,K]
  const float* bias;     // [1024] fp32
  uint16_t* out_bf;      // bf16 out or null
  float*    out_f;       // fp32 out or null
  int act;               // 0 none, 1 relu, 2 tanh
};

template<int AF32, int WF32>
__global__ __launch_bounds__(256) void gemm_k(GemmArgs g0, GemmArgs g1) {
  GemmArgs g = (blockIdx.z == 0) ? g0 : g1;
  const int K = DIM, N = DIM;
  int wave = threadIdx.x >> 6;          // K-slice index
  int lane = threadIdx.x & 63;
  int r    = lane & 15;
  int quad = lane >> 4;
  int m0 = blockIdx.x * 16;
  int n0 = blockIdx.y * 16;
  size_t aoff = (size_t)(m0 + r) * K + wave * 256 + quad * 8;
  size_t woff = (size_t)(n0 + r) * K + wave * 256 + quad * 8;
  const float*    Af = (const float*)g.A    + aoff;
  const uint16_t* Ab = (const uint16_t*)g.A + aoff;
  const float*    Wf = (const float*)g.W    + woff;
  const uint16_t* Wb = (const uint16_t*)g.W + woff;
  f32x4 acc = {0.f, 0.f, 0.f, 0.f};
  #pragma unroll
  for (int k = 0; k < 256; k += 32) {
    bf16x8 a = AF32 ? cvt8(Af + k) : *(const bf16x8*)(Ab + k);
    bf16x8 b = WF32 ? cvt8(Wf + k) : *(const bf16x8*)(Wb + k);
    acc = __builtin_amdgcn_mfma_f32_16x16x32_bf16(a, b, acc, 0, 0, 0);
  }
  // C/D layout: col = lane&15, row = quad*4 + i   [verified m89/m91]
  __shared__ float lds[4][256];
  int li = lane * 4;
  lds[wave][li+0] = acc[0]; lds[wave][li+1] = acc[1];
  lds[wave][li+2] = acc[2]; lds[wave][li+3] = acc[3];
  __syncthreads();
  int t = threadIdx.x;
  float v = lds[0][t] + lds[1][t] + lds[2][t] + lds[3][t];
  int col = (t >> 2) & 15;               // lane&15 of producer
  int row = (t >> 6) * 4 + (t & 3);      // quad*4 + i of producer
  v += g.bias[n0 + col];
  if (g.act == 1) v = fmaxf(v, 0.f);
  else if (g.act == 2) v = tanh_fast(v);
  size_t idx = (size_t)(m0 + row) * N + (n0 + col);
  if (g.out_bf) g.out_bf[idx] = (uint16_t)f2bf(v);
  if (g.out_f)  g.out_f[idx]  = v;
}

// ---------------- scores[b,l] = dot(tanh(embed_row + hoe[b]), Wa) + ba -------
// One wave per (b,l) row; 4 rows per 256-thread block.
// Each wave-load instruction is 64 lanes x 16B contiguous (1 KB).
__global__ __launch_bounds__(256) void scores_k(
    const float* __restrict__ cfe,   // [B,196,1024] fp32 (raw input)
    const float* __restrict__ fre,   // [B,1024] fp32 (ws)
    const float* __restrict__ hoe,   // [B,1024] fp32 (ws)
    const float* __restrict__ Wa,    // [1024] fp32 (raw input)
    const float* __restrict__ ba,    // [1] fp32 (raw input)
    float* __restrict__ scores)      // [B,197]
{
  int row  = blockIdx.x * 4 + (threadIdx.x >> 6);
  int lane = threadIdx.x & 63;
  if (row >= BATCH * LP1) return;
  int b = row / LP1;
  int l = row - b * LP1;

  const float* xrow = (l == 0)
      ? (fre + (size_t)b * DIM)
      : (cfe + ((size_t)b * LCOUNT + (l - 1)) * DIM);
  const float* hrow = hoe + (size_t)b * DIM;
  float sum = 0.f;
  #pragma unroll
  for (int q = 0; q < 4; ++q) {
    int d = q * 256 + lane * 4;          // contiguous 1KB per wave-load
    float4 x = *(const float4*)(xrow + d);
    float4 h = *(const float4*)(hrow + d);
    float4 w = *(const float4*)(Wa + d);
    sum += tanh_fast(x.x + h.x) * w.x;
    sum += tanh_fast(x.y + h.y) * w.y;
    sum += tanh_fast(x.z + h.z) * w.z;
    sum += tanh_fast(x.w + h.w) * w.w;
  }
  #pragma unroll
  for (int off = 32; off > 0; off >>= 1) sum += __shfl_down(sum, off);
  if (lane == 0) scores[row] = sum + ba[0];
}

// ---------------- softmax(scores[b]) fused with visAtt + ho -> attout --------
// grid (128, 4): block handles batch b, 256-dim chunk.
// 4 waves split the 196 conv slots (49 each); each lane holds float4
// (lane covers 4 dims, wave covers the full 256-dim chunk) -> 16B/lane
// coalesced loads + 4x the l-parallelism. LDS cross-wave reduce at the end.
__global__ __launch_bounds__(256) void visatt_k(
    const float*    __restrict__ cf,      // [B,196,1024] fp32 (raw input)
    const uint16_t* __restrict__ frb,     // [B,1024] bf16 (ws)
    const float*    __restrict__ hof,     // [B,1024] fp32 (ws)
    const float*    __restrict__ scores,  // [B,197] (ws)
    uint16_t* __restrict__ attout)        // [B,1024] bf16
{
  int b = blockIdx.x, t = threadIdx.x;
  int lane = t & 63, wave = t >> 6;
  __shared__ float pis[LP1];
  __shared__ float red[4];
  __shared__ float partial[4][256];

  // --- softmax over 197 scores (redundant per y-block; tiny) ---
  float v = (t < LP1) ? scores[b * LP1 + t] : -1e30f;
  float m = v;
  #pragma unroll
  for (int off = 32; off > 0; off >>= 1) m = fmaxf(m, __shfl_down(m, off));
  if (lane == 0) red[wave] = m;
  __syncthreads();
  m = fmaxf(fmaxf(red[0], red[1]), fmaxf(red[2], red[3]));
  float e = (t < LP1) ? __expf(v - m) : 0.f;
  float s = e;
  #pragma unroll
  for (int off = 32; off > 0; off >>= 1) s += __shfl_down(s, off);
  __syncthreads();
  if (lane == 0) red[wave] = s;
  __syncthreads();
  s = red[0] + red[1] + red[2] + red[3];
  if (t < LP1) pis[t] = e / s;
  __syncthreads();

  // --- weighted sum over l: wave w handles l in [w*49, w*49+49) ---
  int d0 = blockIdx.y * 256 + lane * 4;
  const float* base = cf + ((size_t)b * LCOUNT + wave * 49) * DIM + d0;
  f32x4 acc = {0.f, 0.f, 0.f, 0.f};
  #pragma unroll 7
  for (int l = 0; l < 49; ++l) {
    float4 x = *(const float4*)(base + (size_t)l * DIM);
    float p = pis[wave * 49 + l + 1];     // LDS broadcast (conflict-free)
    acc[0] += p * x.x; acc[1] += p * x.y;
    acc[2] += p * x.z; acc[3] += p * x.w;
  }
  int li = lane * 4;
  partial[wave][li+0] = acc[0]; partial[wave][li+1] = acc[1];
  partial[wave][li+2] = acc[2]; partial[wave][li+3] = acc[3];
  __syncthreads();

  // --- cross-wave reduce + fr slot + ho residual, store bf16 ---
  float vsum = partial[0][t] + partial[1][t] + partial[2][t] + partial[3][t];
  int d = blockIdx.y * 256 + t;
  vsum += pis[0] * bf2f(frb[b * DIM + d]);
  vsum += hof[b * DIM + d];
  attout[b * DIM + d] = (uint16_t)f2bf(vsum);
}

// ---------------- launch -----------------------------------------------------
extern "C" void kernel_launch(void* const* d_in, const int* in_sizes, int n_in,
                              void* d_out, int out_size, void* d_ws, size_t ws_size,
                              hipStream_t stream) {
  const float* h_out       = (const float*)d_in[0];
  const float* fake_region = (const float*)d_in[1];
  const float* conv_feat   = (const float*)d_in[2];
  const float* conv_feat_e = (const float*)d_in[3];
  const float* W_fr  = (const float*)d_in[4];
  const float* b_fr  = (const float*)d_in[5];
  const float* W_fre = (const float*)d_in[6];
  const float* b_fre = (const float*)d_in[7];
  const float* W_ho  = (const float*)d_in[8];
  const float* b_ho  = (const float*)d_in[9];
  const float* W_hoe = (const float*)d_in[10];
  const float* b_hoe = (const float*)d_in[11];
  const float* W_a   = (const float*)d_in[12];
  const float* b_a   = (const float*)d_in[13];
  const float* W_h   = (const float*)d_in[14];
  const float* b_h   = (const float*)d_in[15];

  char* ws = (char*)d_ws;
  uint16_t* fr_bf   = (uint16_t*)(ws + 0);        // 256 KB [128,1024] bf16
  uint16_t* ho_bf   = (uint16_t*)(ws + 262144);   // 256 KB
  uint16_t* attout  = (uint16_t*)(ws + 524288);   // 256 KB
  float*    ho_f    = (float*)   (ws + 786432);   // 512 KB [128,1024] fp32
  float*    fre_f   = (float*)   (ws + 1310720);  // 512 KB
  float*    hoe_f   = (float*)   (ws + 1835008);  // 512 KB
  float*    scores  = (float*)   (ws + 2359296);  // ~100 KB [128,197]

  dim3 blk(256);

  // 1: fr = relu(fake_region@W_fr^T+b), ho = tanh(h_out@W_ho^T+b)
  //    A and W both fp32, converted in-register (cvt_k eliminated).
  GemmArgs ga{fake_region, W_fr, b_fr, fr_bf, nullptr, 1};
  GemmArgs gb{h_out,       W_ho, b_ho, ho_bf, ho_f,    2};
  gemm_k<1,1><<<dim3(8, 64, 2), blk, 0, stream>>>(ga, gb);

  // 2: fr_e = fr@W_fre^T+b, ho_e = ho@W_hoe^T+b  (fp32 outputs)
  GemmArgs gc{fr_bf, W_fre, b_fre, nullptr, fre_f, 0};
  GemmArgs gd{ho_bf, W_hoe, b_hoe, nullptr, hoe_f, 0};
  gemm_k<0,1><<<dim3(8, 64, 2), blk, 0, stream>>>(gc, gd);

  // 3: attention scores over L+1 = 197 slots
  int nrows = BATCH * LP1;                      // 25216, divisible by 4
  scores_k<<<dim3(nrows / 4), blk, 0, stream>>>(conv_feat_e, fre_f, hoe_f,
                                                W_a, b_a, scores);

  // 4: softmax + visAtt + ho -> attout (bf16)
  visatt_k<<<dim3(BATCH, 4), blk, 0, stream>>>(conv_feat, fr_bf, ho_f,
                                               scores, attout);

  // 5: h = tanh(attout@W_h^T + b_h) -> d_out (fp32)
  GemmArgs ge{attout, W_h, b_h, nullptr, (float*)d_out, 2};
  gemm_k<0,1><<<dim3(8, 64, 1), blk, 0, stream>>>(ge, ge);
}